// Round 19
// baseline (561.375 us; speedup 1.0000x reference)
//
#include <hip/hip_runtime.h>
#include <math.h>

#define BB   64
#define NPG0 400
#define DD   128
#define HH   4
#define CC   32
#define HIDD 64
#define POSD 16
#define EE   409600
#define EG   6400

// ---------------- pos enc: out = x + lap @ Wpos + bpos ----------------
__global__ void k_pos(const float* __restrict__ x, const float* __restrict__ lap,
                      const float* __restrict__ Wp, const float* __restrict__ bp,
                      float* __restrict__ out, int N){
  __shared__ float W[POSD*DD];
  __shared__ float bsh[DD];
  for(int i=threadIdx.x;i<POSD*DD;i+=blockDim.x) W[i]=Wp[i];
  for(int i=threadIdx.x;i<DD;i+=blockDim.x) bsh[i]=bp[i];
  __syncthreads();
  int total=N*DD;
  for(int idx=blockIdx.x*blockDim.x+threadIdx.x; idx<total; idx+=gridDim.x*blockDim.x){
    int n=idx>>7, d=idx&127;
    const float* lr=lap+(size_t)n*POSD;
    float acc=bsh[d]+x[idx];
    #pragma unroll
    for(int p=0;p<POSD;p++) acc=fmaf(lr[p],W[p*DD+d],acc);
    out[idx]=acc;
  }
}

// ======== QKVS GEMM, 2-D grid: blockIdx.y selects matrix (4x wave parallelism) ====
// BM=64, 512 thr = 8 waves; wave w owns cols [w*16,(w+1)*16); lane = row.
__global__ __launch_bounds__(512) void k_gemm4_sw(
    const float* __restrict__ X,
    const float* __restrict__ W0,const float* __restrict__ W1,
    const float* __restrict__ W2,const float* __restrict__ W3,
    const float* __restrict__ b0,const float* __restrict__ b1,
    const float* __restrict__ b2,const float* __restrict__ b3,
    float* __restrict__ Y0,float* __restrict__ Y1,
    float* __restrict__ Y2,float* __restrict__ Y3){
  constexpr int XPAD=DD+4;
  __shared__ float Xl[64*XPAD];
  int my=blockIdx.y;
  const float* Wg  =(my==0)?W0:(my==1)?W1:(my==2)?W2:W3;
  const float* bias=(my==0)?b0:(my==1)?b1:(my==2)?b2:b3;
  float*       Y   =(my==0)?Y0:(my==1)?Y1:(my==2)?Y2:Y3;
  int tid=threadIdx.x;
  { const float4* xs=(const float4*)(X+(size_t)blockIdx.x*64*DD);
    for(int i=tid;i<64*32;i+=512){
      int r=i>>5, kq=i&31;
      *(float4*)&Xl[r*XPAD+kq*4]=xs[i];
    } }
  __syncthreads();
  int lane=tid&63;
  int wv=__builtin_amdgcn_readfirstlane(tid>>6);
  int cbase=wv*16;
  int row=blockIdx.x*64+lane;
  const float* xr=&Xl[lane*XPAD];
  float acc[16];
  #pragma unroll
  for(int c=0;c<16;c++) acc[c]=0.f;
  #pragma unroll 2
  for(int kt=0;kt<32;kt++){
    float4 xv=*(const float4*)&xr[4*kt];
    float xk[4]={xv.x,xv.y,xv.z,xv.w};
    #pragma unroll
    for(int kk=0;kk<4;kk++){
      const float4* wrow=(const float4*)(Wg+(size_t)(4*kt+kk)*DD+cbase);
      #pragma unroll
      for(int cg=0;cg<4;cg++){
        float4 w4=wrow[cg];
        acc[cg*4+0]=fmaf(xk[kk],w4.x,acc[cg*4+0]);
        acc[cg*4+1]=fmaf(xk[kk],w4.y,acc[cg*4+1]);
        acc[cg*4+2]=fmaf(xk[kk],w4.z,acc[cg*4+2]);
        acc[cg*4+3]=fmaf(xk[kk],w4.w,acc[cg*4+3]);
      }
    }
  }
  const float4* bb4=(const float4*)(bias+cbase);
  #pragma unroll
  for(int cg=0;cg<4;cg++){
    float4 b4=bb4[cg];
    float4 v;
    v.x=acc[cg*4+0]+b4.x; v.y=acc[cg*4+1]+b4.y;
    v.z=acc[cg*4+2]+b4.z; v.w=acc[cg*4+3]+b4.w;
    *(float4*)&Y[(size_t)row*DD+cbase+cg*4]=v;
  }
}

// ---- fused FFN chain, 1024 threads = 16 waves (2x wave parallelism) ----
// wave owns 8 cols (stages A/C) / 4 cols (stage B); cbase wave-uniform -> scalar W.
// t2=LN(X@Wlo+b+resid); h=relu(t2@W1+b1); out=LN(h@W2+b2+t2)
__global__ __launch_bounds__(1024) void k_ffn_fused(
    const float* __restrict__ Xg, const float* __restrict__ resid,
    const float* __restrict__ Wlo, const float* __restrict__ blo,
    const float* __restrict__ l1g, const float* __restrict__ l1b,
    const float* __restrict__ W1, const float* __restrict__ b1,
    const float* __restrict__ W2, const float* __restrict__ b2,
    const float* __restrict__ l2g, const float* __restrict__ l2b,
    float* __restrict__ Y){
  constexpr int XPAD=DD+4;
  constexpr int HPAD=HIDD+4;
  __shared__ float Xa[64*XPAD];
  __shared__ float hb[64*HPAD];
  __shared__ float redA[16*64];
  __shared__ float redB[16*64];
  int tid=threadIdx.x;
  { const float4* xs=(const float4*)(Xg+(size_t)blockIdx.x*64*DD);
    for(int i=tid;i<64*32;i+=1024){
      int r=i>>5, kq=i&31;
      *(float4*)&Xa[r*XPAD+kq*4]=xs[i];
    } }
  __syncthreads();
  int lane=tid&63;
  int wv=__builtin_amdgcn_readfirstlane(tid>>6);   // 0..15
  int row=blockIdx.x*64+lane;
  const float* xr=&Xa[lane*XPAD];

  // ---- stage A: 8 cols [wv*8,+8) of X@Wlo + blo + resid, LN -> t2 in place ----
  int cbase=wv*8;
  float acc[8];
  #pragma unroll
  for(int c=0;c<8;c++) acc[c]=0.f;
  #pragma unroll 2
  for(int kt=0;kt<32;kt++){
    float4 xv=*(const float4*)&xr[4*kt];
    float xk[4]={xv.x,xv.y,xv.z,xv.w};
    #pragma unroll
    for(int kk=0;kk<4;kk++){
      const float4* wrow=(const float4*)(Wlo+(size_t)(4*kt+kk)*DD+cbase);
      #pragma unroll
      for(int cg=0;cg<2;cg++){
        float4 w4=wrow[cg];
        acc[cg*4+0]=fmaf(xk[kk],w4.x,acc[cg*4+0]);
        acc[cg*4+1]=fmaf(xk[kk],w4.y,acc[cg*4+1]);
        acc[cg*4+2]=fmaf(xk[kk],w4.z,acc[cg*4+2]);
        acc[cg*4+3]=fmaf(xk[kk],w4.w,acc[cg*4+3]);
      }
    }
  }
  { const float4* bb4=(const float4*)(blo+cbase);
    #pragma unroll
    for(int cg=0;cg<2;cg++){
      float4 b4=bb4[cg];
      float4 rv=*(const float4*)&resid[(size_t)row*DD+cbase+cg*4];
      acc[cg*4+0]+=b4.x+rv.x; acc[cg*4+1]+=b4.y+rv.y;
      acc[cg*4+2]+=b4.z+rv.z; acc[cg*4+3]+=b4.w+rv.w;
    } }
  { float ps=0.f,pq=0.f;
    #pragma unroll
    for(int c=0;c<8;c++){ ps+=acc[c]; pq+=acc[c]*acc[c]; }
    redA[wv*64+lane]=ps; redB[wv*64+lane]=pq;
    __syncthreads();
    float s=0.f,q=0.f;
    #pragma unroll
    for(int w=0;w<16;w++){ s+=redA[w*64+lane]; q+=redB[w*64+lane]; }
    float mu=s*(1.f/DD);
    float inv=1.0f/sqrtf(q*(1.f/DD)-mu*mu+1e-5f);
    const float4* g4p=(const float4*)(l1g+cbase);
    const float4* e4p=(const float4*)(l1b+cbase);
    #pragma unroll
    for(int cg=0;cg<2;cg++){
      float4 g4=g4p[cg], e4=e4p[cg];
      float4 v;
      v.x=(acc[cg*4+0]-mu)*inv*g4.x+e4.x;
      v.y=(acc[cg*4+1]-mu)*inv*g4.y+e4.y;
      v.z=(acc[cg*4+2]-mu)*inv*g4.z+e4.z;
      v.w=(acc[cg*4+3]-mu)*inv*g4.w+e4.w;
      *(float4*)&Xa[lane*XPAD+cbase+cg*4]=v;
    } }
  __syncthreads();

  // ---- stage B: 4 cols [wv*4,+4) of h = relu(t2 @ W1 + b1) ----
  { int cb2=wv*4;
    float acc2[4];
    #pragma unroll
    for(int c=0;c<4;c++) acc2[c]=0.f;
    #pragma unroll 2
    for(int kt=0;kt<32;kt++){
      float4 xv=*(const float4*)&xr[4*kt];
      float xk[4]={xv.x,xv.y,xv.z,xv.w};
      #pragma unroll
      for(int kk=0;kk<4;kk++){
        float4 w4=*(const float4*)(W1+(size_t)(4*kt+kk)*HIDD+cb2);
        acc2[0]=fmaf(xk[kk],w4.x,acc2[0]);
        acc2[1]=fmaf(xk[kk],w4.y,acc2[1]);
        acc2[2]=fmaf(xk[kk],w4.z,acc2[2]);
        acc2[3]=fmaf(xk[kk],w4.w,acc2[3]);
      }
    }
    float4 b4=*(const float4*)(b1+cb2);
    float4 v;
    v.x=fmaxf(acc2[0]+b4.x,0.f); v.y=fmaxf(acc2[1]+b4.y,0.f);
    v.z=fmaxf(acc2[2]+b4.z,0.f); v.w=fmaxf(acc2[3]+b4.w,0.f);
    *(float4*)&hb[lane*HPAD+cb2]=v;
  }
  __syncthreads();

  // ---- stage C: 8 cols [wv*8,+8) of LN(h @ W2 + b2 + t2) ----
  { float acc3[8];
    #pragma unroll
    for(int c=0;c<8;c++) acc3[c]=0.f;
    const float* hr=&hb[lane*HPAD];
    #pragma unroll 2
    for(int kt=0;kt<16;kt++){
      float4 xv=*(const float4*)&hr[4*kt];
      float xk[4]={xv.x,xv.y,xv.z,xv.w};
      #pragma unroll
      for(int kk=0;kk<4;kk++){
        const float4* wrow=(const float4*)(W2+(size_t)(4*kt+kk)*DD+cbase);
        #pragma unroll
        for(int cg=0;cg<2;cg++){
          float4 w4=wrow[cg];
          acc3[cg*4+0]=fmaf(xk[kk],w4.x,acc3[cg*4+0]);
          acc3[cg*4+1]=fmaf(xk[kk],w4.y,acc3[cg*4+1]);
          acc3[cg*4+2]=fmaf(xk[kk],w4.z,acc3[cg*4+2]);
          acc3[cg*4+3]=fmaf(xk[kk],w4.w,acc3[cg*4+3]);
        }
      }
    }
    const float4* bb4=(const float4*)(b2+cbase);
    #pragma unroll
    for(int cg=0;cg<2;cg++){
      float4 b4=bb4[cg];
      float4 rv=*(const float4*)&Xa[lane*XPAD+cbase+cg*4];
      acc3[cg*4+0]+=b4.x+rv.x; acc3[cg*4+1]+=b4.y+rv.y;
      acc3[cg*4+2]+=b4.z+rv.z; acc3[cg*4+3]+=b4.w+rv.w;
    }
    float ps=0.f,pq=0.f;
    #pragma unroll
    for(int c=0;c<8;c++){ ps+=acc3[c]; pq+=acc3[c]*acc3[c]; }
    __syncthreads();
    redA[wv*64+lane]=ps; redB[wv*64+lane]=pq;
    __syncthreads();
    float s=0.f,q=0.f;
    #pragma unroll
    for(int w=0;w<16;w++){ s+=redA[w*64+lane]; q+=redB[w*64+lane]; }
    float mu=s*(1.f/DD);
    float inv=1.0f/sqrtf(q*(1.f/DD)-mu*mu+1e-5f);
    const float4* g4p=(const float4*)(l2g+cbase);
    const float4* e4p=(const float4*)(l2b+cbase);
    #pragma unroll
    for(int cg=0;cg<2;cg++){
      float4 g4=g4p[cg], e4=e4p[cg];
      float4 v;
      v.x=(acc3[cg*4+0]-mu)*inv*g4.x+e4.x;
      v.y=(acc3[cg*4+1]-mu)*inv*g4.y+e4.y;
      v.z=(acc3[cg*4+2]-mu)*inv*g4.z+e4.z;
      v.w=(acc3[cg*4+3]-mu)*inv*g4.w+e4.w;
      *(float4*)&Y[(size_t)row*DD+cbase+cg*4]=v;
    } }
}

// ---------------- per-graph destination-CSR with fused remap ----------------
__global__ __launch_bounds__(512) void k_csr(const int* __restrict__ src,const int* __restrict__ dst,
   const int* __restrict__ msk,const int* __restrict__ kept,const int* __restrict__ nid,int n,
   int* __restrict__ rowstart,int* __restrict__ rowcnt,int* __restrict__ esrc,
   int* __restrict__ nsrc,int* __restrict__ ndst,int* __restrict__ nmsk){
  __shared__ int cnt[512];
  __shared__ int woff[512];
  int b=blockIdx.x, t=threadIdx.x;
  cnt[t]=0;
  __syncthreads();
  int ebase=b*EG, nbase=b*n;
  for(int j=t;j<EG;j+=512){
    int e=ebase+j;
    int s,d,m;
    if(kept){
      int s0=src[e], d0=dst[e];
      m=(msk?msk[e]:1) && kept[s0] && kept[d0];
      s=m?nid[s0]:0; d=m?nid[d0]:0;
      nsrc[e]=s; ndst[e]=d; nmsk[e]=m;
    } else { s=src[e]; d=dst[e]; m=1; }
    if(m) atomicAdd(&cnt[d-nbase],1);
  }
  __syncthreads();
  int v=cnt[t];
  woff[t]=v;
  __syncthreads();
  for(int off=1;off<512;off<<=1){
    int a=(t>=off)?woff[t-off]:0;
    __syncthreads();
    woff[t]+=a;
    __syncthreads();
  }
  int excl=woff[t]-v;
  if(t<n){ rowstart[nbase+t]=ebase+excl; rowcnt[nbase+t]=v; }
  __syncthreads();
  woff[t]=excl;
  __syncthreads();
  for(int j=t;j<EG;j+=512){
    int e=ebase+j;
    int s,d,m;
    if(kept){ m=nmsk[e]; s=nsrc[e]; d=ndst[e]; }
    else { m=1; s=src[e]; d=dst[e]; }
    if(!m) continue;
    int off=atomicAdd(&woff[d-nbase],1);
    esrc[ebase+off]=s;
  }
}

// ---------------- fused attention: one LANE per (node,head), padded K/V in LDS ----
template<int NG>
__global__ __launch_bounds__(512) void k_attn4(const float* __restrict__ q,const float* __restrict__ kk,
     const float* __restrict__ v,const int* __restrict__ rowstart,const int* __restrict__ rowcnt,
     const int* __restrict__ esrc,float* __restrict__ attn){
  __shared__ float4 kl[NG*9];
  __shared__ float4 vl[NG*9];
  int b=blockIdx.x>>2, h=blockIdx.x&3;
  int nb=b*NG;
  const float4* kg=(const float4*)kk;
  const float4* vg=(const float4*)v;
  for(int i=threadIdx.x;i<NG*8;i+=512){
    int node=i>>3, qq=i&7;
    size_t gidx=(size_t)(nb+node)*32 + h*8 + qq;
    kl[node*9+qq]=kg[gidx];
    vl[node*9+qq]=vg[gidx];
  }
  __syncthreads();
  int node=threadIdx.x;
  if(node>=NG) return;
  int gn=nb+node;
  float4 q0,q1,q2,q3,q4,q5,q6,q7;
  { const float4* qp=(const float4*)(q+(size_t)gn*DD+h*CC);
    q0=qp[0];q1=qp[1];q2=qp[2];q3=qp[3];q4=qp[4];q5=qp[5];q6=qp[6];q7=qp[7]; }
  int st=rowstart[gn], cn=rowcnt[gn];
  float m=-1e30f, s=0.f;
  float4 o0={0,0,0,0},o1={0,0,0,0},o2={0,0,0,0},o3={0,0,0,0};
  float4 o4={0,0,0,0},o5={0,0,0,0},o6={0,0,0,0},o7={0,0,0,0};
  for(int j=0;j<cn;j++){
    int sl=esrc[st+j]-nb;
    const float4* kr=&kl[sl*9];
    float4 k0=kr[0],k1=kr[1],k2=kr[2],k3=kr[3],k4=kr[4],k5=kr[5],k6=kr[6],k7=kr[7];
    float a0=q0.x*k0.x+q0.y*k0.y+q0.z*k0.z+q0.w*k0.w;
    float a1=q1.x*k1.x+q1.y*k1.y+q1.z*k1.z+q1.w*k1.w;
    float a2=q2.x*k2.x+q2.y*k2.y+q2.z*k2.z+q2.w*k2.w;
    float a3=q3.x*k3.x+q3.y*k3.y+q3.z*k3.z+q3.w*k3.w;
    a0+=q4.x*k4.x+q4.y*k4.y+q4.z*k4.z+q4.w*k4.w;
    a1+=q5.x*k5.x+q5.y*k5.y+q5.z*k5.z+q5.w*k5.w;
    a2+=q6.x*k6.x+q6.y*k6.y+q6.z*k6.z+q6.w*k6.w;
    a3+=q7.x*k7.x+q7.y*k7.y+q7.z*k7.z+q7.w*k7.w;
    float lg=((a0+a1)+(a2+a3))*0.17677669529663687f;
    const float4* vr=&vl[sl*9];
    float4 v0=vr[0],v1=vr[1],v2=vr[2],v3=vr[3],v4=vr[4],v5=vr[5],v6=vr[6],v7=vr[7];
    if(lg<=m){
      float w=__expf(lg-m);
      s+=w;
      o0.x=fmaf(w,v0.x,o0.x);o0.y=fmaf(w,v0.y,o0.y);o0.z=fmaf(w,v0.z,o0.z);o0.w=fmaf(w,v0.w,o0.w);
      o1.x=fmaf(w,v1.x,o1.x);o1.y=fmaf(w,v1.y,o1.y);o1.z=fmaf(w,v1.z,o1.z);o1.w=fmaf(w,v1.w,o1.w);
      o2.x=fmaf(w,v2.x,o2.x);o2.y=fmaf(w,v2.y,o2.y);o2.z=fmaf(w,v2.z,o2.z);o2.w=fmaf(w,v2.w,o2.w);
      o3.x=fmaf(w,v3.x,o3.x);o3.y=fmaf(w,v3.y,o3.y);o3.z=fmaf(w,v3.z,o3.z);o3.w=fmaf(w,v3.w,o3.w);
      o4.x=fmaf(w,v4.x,o4.x);o4.y=fmaf(w,v4.y,o4.y);o4.z=fmaf(w,v4.z,o4.z);o4.w=fmaf(w,v4.w,o4.w);
      o5.x=fmaf(w,v5.x,o5.x);o5.y=fmaf(w,v5.y,o5.y);o5.z=fmaf(w,v5.z,o5.z);o5.w=fmaf(w,v5.w,o5.w);
      o6.x=fmaf(w,v6.x,o6.x);o6.y=fmaf(w,v6.y,o6.y);o6.z=fmaf(w,v6.z,o6.z);o6.w=fmaf(w,v6.w,o6.w);
      o7.x=fmaf(w,v7.x,o7.x);o7.y=fmaf(w,v7.y,o7.y);o7.z=fmaf(w,v7.z,o7.z);o7.w=fmaf(w,v7.w,o7.w);
    } else {
      float r=__expf(m-lg);
      s=fmaf(s,r,1.f);
      o0.x=fmaf(o0.x,r,v0.x);o0.y=fmaf(o0.y,r,v0.y);o0.z=fmaf(o0.z,r,v0.z);o0.w=fmaf(o0.w,r,v0.w);
      o1.x=fmaf(o1.x,r,v1.x);o1.y=fmaf(o1.y,r,v1.y);o1.z=fmaf(o1.z,r,v1.z);o1.w=fmaf(o1.w,r,v1.w);
      o2.x=fmaf(o2.x,r,v2.x);o2.y=fmaf(o2.y,r,v2.y);o2.z=fmaf(o2.z,r,v2.z);o2.w=fmaf(o2.w,r,v2.w);
      o3.x=fmaf(o3.x,r,v3.x);o3.y=fmaf(o3.y,r,v3.y);o3.z=fmaf(o3.z,r,v3.z);o3.w=fmaf(o3.w,r,v3.w);
      o4.x=fmaf(o4.x,r,v4.x);o4.y=fmaf(o4.y,r,v4.y);o4.z=fmaf(o4.z,r,v4.z);o4.w=fmaf(o4.w,r,v4.w);
      o5.x=fmaf(o5.x,r,v5.x);o5.y=fmaf(o5.y,r,v5.y);o5.z=fmaf(o5.z,r,v5.z);o5.w=fmaf(o5.w,r,v5.w);
      o6.x=fmaf(o6.x,r,v6.x);o6.y=fmaf(o6.y,r,v6.y);o6.z=fmaf(o6.z,r,v6.z);o6.w=fmaf(o6.w,r,v6.w);
      o7.x=fmaf(o7.x,r,v7.x);o7.y=fmaf(o7.y,r,v7.y);o7.z=fmaf(o7.z,r,v7.z);o7.w=fmaf(o7.w,r,v7.w);
      m=lg;
    }
  }
  float inv=(s>0.f)?(1.f/s):0.f;
  float* op=attn+(size_t)gn*DD+h*CC;
  float4* op4=(float4*)op;
  float4 r0=op4[0],r1=op4[1],r2=op4[2],r3=op4[3],r4=op4[4],r5=op4[5],r6=op4[6],r7=op4[7];
  r0.x+=o0.x*inv;r0.y+=o0.y*inv;r0.z+=o0.z*inv;r0.w+=o0.w*inv;
  r1.x+=o1.x*inv;r1.y+=o1.y*inv;r1.z+=o1.z*inv;r1.w+=o1.w*inv;
  r2.x+=o2.x*inv;r2.y+=o2.y*inv;r2.z+=o2.z*inv;r2.w+=o2.w*inv;
  r3.x+=o3.x*inv;r3.y+=o3.y*inv;r3.z+=o3.z*inv;r3.w+=o3.w*inv;
  r4.x+=o4.x*inv;r4.y+=o4.y*inv;r4.z+=o4.z*inv;r4.w+=o4.w*inv;
  r5.x+=o5.x*inv;r5.y+=o5.y*inv;r5.z+=o5.z*inv;r5.w+=o5.w*inv;
  r6.x+=o6.x*inv;r6.y+=o6.y*inv;r6.z+=o6.z*inv;r6.w+=o6.w*inv;
  r7.x+=o7.x*inv;r7.y+=o7.y*inv;r7.z+=o7.z*inv;r7.w+=o7.w*inv;
  op4[0]=r0;op4[1]=r1;op4[2]=r2;op4[3]=r3;op4[4]=r4;op4[5]=r5;op4[6]=r6;op4[7]=r7;
}

// ---------------- fused SAGPool scorer + top-k (block per graph) ----------------
__global__ __launch_bounds__(512) void k_sagtopk(const float* __restrict__ x,
   const float* __restrict__ wrel,const float* __restrict__ wroot,const float* __restrict__ brel,
   const int* __restrict__ rowstart,const int* __restrict__ rowcnt,const int* __restrict__ esrc,
   int n,int k,float* __restrict__ tv,int* __restrict__ gi,
   int* __restrict__ kept,int* __restrict__ nid){
  __shared__ float pnl[NPG0];
  __shared__ float sv[512];
  __shared__ int   si[512];
  int b=blockIdx.x, t=threadIdx.x, nbase=b*n;
  float rdot=0.f;
  if(t<n){
    const float4* xr=(const float4*)(x+(size_t)(nbase+t)*DD);
    float p=0.f;
    #pragma unroll
    for(int qq=0;qq<32;qq++){
      float4 xv=xr[qq];
      float4 wr=((const float4*)wrel)[qq];
      float4 wo=((const float4*)wroot)[qq];
      p   =fmaf(xv.x,wr.x,fmaf(xv.y,wr.y,fmaf(xv.z,wr.z,fmaf(xv.w,wr.w,p))));
      rdot=fmaf(xv.x,wo.x,fmaf(xv.y,wo.y,fmaf(xv.z,wo.z,fmaf(xv.w,wo.w,rdot))));
    }
    pnl[t]=p;
  }
  __syncthreads();
  float sc=-INFINITY;
  if(t<n){
    int st=rowstart[nbase+t], cn=rowcnt[nbase+t];
    float s=0.f;
    for(int j=0;j<cn;j++) s+=pnl[esrc[st+j]-nbase];
    sc=tanhf(s+brel[0]+rdot);
  }
  sv[t]=(t<n)?sc:-INFINITY;
  si[t]=t;
  for(int ksz=2;ksz<=512;ksz<<=1){
    for(int j=ksz>>1;j>0;j>>=1){
      __syncthreads();
      int ixj=t^j;
      if(ixj>t){
        float s1=sv[t], s2=sv[ixj];
        int i1=si[t], i2=si[ixj];
        bool firstRanks=(s1>s2)||(s1==s2&&i1<i2);
        bool up=((t&ksz)==0);
        if(up? !firstRanks : firstRanks){ sv[t]=s2;sv[ixj]=s1;si[t]=i2;si[ixj]=i1; }
      }
    }
  }
  __syncthreads();
  if(t<k){
    int oldg=nbase+si[t];
    tv[b*k+t]=sv[t];
    gi[b*k+t]=oldg;
    kept[oldg]=1;
    nid[oldg]=b*k+t;
  } else if(t<n){
    kept[nbase+si[t]]=0;
  }
}

// ---------------- gather (parallel) ----------------
__global__ void k_gather(const float* __restrict__ xin, const int* __restrict__ gi,
                         const float* __restrict__ tv, float* __restrict__ xout, int rows){
  int idx=blockIdx.x*blockDim.x+threadIdx.x;
  if(idx>=rows*DD) return;
  int r=idx>>7;
  int d=idx&127;
  xout[idx]=xin[(size_t)gi[r]*DD+d]*tv[r];
}

// ---------------- readout (4 j-strips x 128 channels per block) ----------------
__global__ __launch_bounds__(512) void k_readout(const float* __restrict__ xk, int k,
                                                 float* __restrict__ xf){
  __shared__ float pm[512];
  __shared__ float ps[512];
  int b=blockIdx.x, t=threadIdx.x;
  int d=t&127, strip=t>>7;
  const float* base=xk+((size_t)b*k)*DD+d;
  float mx=-INFINITY, sm=0.f;
  for(int j=strip;j<k;j+=4){
    float v=base[(size_t)j*DD];
    mx=fmaxf(mx,v); sm+=v;
  }
  pm[t]=mx; ps[t]=sm;
  __syncthreads();
  if(t<128){
    float m0=fmaxf(fmaxf(pm[t],pm[t+128]),fmaxf(pm[t+256],pm[t+384]));
    float s0=ps[t]+ps[t+128]+ps[t+256]+ps[t+384];
    xf[b*256+t]+=m0;
    xf[b*256+128+t]+=s0/(float)k;
  }
}

// ---------------- head (parallel, unfused) ----------------
__global__ void k_h1(const float* __restrict__ xf,const float* __restrict__ W,const float* __restrict__ b,float* __restrict__ z){
  int i=blockIdx.x*blockDim.x+threadIdx.x; if(i>=BB*DD) return;
  int r=i>>7, j=i&127;
  float acc=b[j];
  const float* xr=xf+r*256;
  #pragma unroll 8
  for(int t=0;t<256;t++) acc=fmaf(xr[t], W[t*DD+j], acc);
  z[i]=acc;
}
__global__ void k_bnrelu(const float* __restrict__ z,const float* __restrict__ g,const float* __restrict__ be,
                         float* __restrict__ h,int cols){
  int j=blockIdx.x*blockDim.x+threadIdx.x; if(j>=cols) return;
  float mu=0.f;
  for(int r=0;r<BB;r++) mu+=z[r*cols+j];
  mu*=(1.f/BB);
  float var=0.f;
  for(int r=0;r<BB;r++){ float d=z[r*cols+j]-mu; var+=d*d; }
  var*=(1.f/BB);
  float inv=1.0f/sqrtf(var+1e-5f);
  float gg=g[j], bb=be[j];
  for(int r=0;r<BB;r++){ float y=(z[r*cols+j]-mu)*inv*gg+bb; h[r*cols+j]=fmaxf(y,0.f); }
}
__global__ void k_h2(const float* __restrict__ h1,const float* __restrict__ W,const float* __restrict__ b,float* __restrict__ z){
  int i=blockIdx.x*blockDim.x+threadIdx.x; if(i>=BB*HIDD) return;
  int r=i>>6, j=i&63;
  float acc=b[j];
  #pragma unroll 8
  for(int t=0;t<DD;t++) acc=fmaf(h1[r*DD+t], W[t*HIDD+j], acc);
  z[i]=acc;
}
__global__ void k_h3(const float* __restrict__ h2,const float* __restrict__ W,const float* __restrict__ b,float* __restrict__ out){
  int bi=threadIdx.x; if(bi>=BB) return;
  float acc=b[0];
  for(int t=0;t<HIDD;t++) acc=fmaf(h2[bi*HIDD+t], W[t], acc);
  out[bi]=acc;
}

extern "C" void kernel_launch(void* const* d_in, const int* in_sizes, int n_in,
                              void* d_out, int out_size, void* d_ws, size_t ws_size,
                              hipStream_t stream){
  (void)in_sizes; (void)n_in; (void)out_size; (void)ws_size;
  const float* x_in =(const float*)d_in[0];
  const float* lap  =(const float*)d_in[1];
  const int*   esrc0=(const int*)  d_in[2];
  const int*   edst0=(const int*)  d_in[3];
  const float* Wpos =(const float*)d_in[4];
  const float* bpos =(const float*)d_in[5];
  const float* gWq  =(const float*)d_in[6];
  const float* gbq  =(const float*)d_in[7];
  const float* gWk  =(const float*)d_in[8];
  const float* gbk  =(const float*)d_in[9];
  const float* gWv  =(const float*)d_in[10];
  const float* gbv  =(const float*)d_in[11];
  const float* gWs  =(const float*)d_in[12];
  const float* gbs  =(const float*)d_in[13];
  const float* gWlo =(const float*)d_in[14];
  const float* gblo =(const float*)d_in[15];
  const float* gl1g =(const float*)d_in[16];
  const float* gl1b =(const float*)d_in[17];
  const float* gW1  =(const float*)d_in[18];
  const float* gb1  =(const float*)d_in[19];
  const float* gW2  =(const float*)d_in[20];
  const float* gb2  =(const float*)d_in[21];
  const float* gl2g =(const float*)d_in[22];
  const float* gl2b =(const float*)d_in[23];
  const float* pWrel=(const float*)d_in[24];
  const float* pbrel=(const float*)d_in[25];
  const float* pWrt =(const float*)d_in[26];
  const float* hW1  =(const float*)d_in[27];
  const float* hb1  =(const float*)d_in[28];
  const float* hW2  =(const float*)d_in[29];
  const float* hb2  =(const float*)d_in[30];
  const float* hW3  =(const float*)d_in[31];
  const float* hb3  =(const float*)d_in[32];
  const float* bn1g =(const float*)d_in[33];
  const float* bn1b =(const float*)d_in[34];
  const float* bn2g =(const float*)d_in[35];
  const float* bn2b =(const float*)d_in[36];
  float* out=(float*)d_out;

  // ---- workspace arena ----
  char* base=(char*)d_ws; size_t off=0;
  auto alloc=[&](size_t bytes)->void*{ void* p=base+off; off+=(bytes+255)&~(size_t)255; return p; };
  const int NMAX=BB*NPG0; // 25600
  float* xA  =(float*)alloc((size_t)NMAX*DD*4);
  float* qb  =(float*)alloc((size_t)NMAX*DD*4);
  float* kb  =(float*)alloc((size_t)NMAX*DD*4);
  float* vb  =(float*)alloc((size_t)NMAX*DD*4);
  float* xO  =(float*)alloc((size_t)NMAX*DD*4);   // skip/attn/block-output
  int*   rowstart=(int*)alloc((size_t)NMAX*4);
  int*   rowcnt  =(int*)alloc((size_t)NMAX*4);
  int*   esrcW   =(int*)alloc((size_t)EE*4);
  float* tvb =(float*)alloc((size_t)BB*320*4);
  int*   gib =(int*)  alloc((size_t)BB*320*4);
  int*   kept=(int*)  alloc((size_t)NMAX*4);
  int*   nid =(int*)  alloc((size_t)NMAX*4);
  int*   srcA=(int*)  alloc((size_t)EE*4);
  int*   dstA=(int*)  alloc((size_t)EE*4);
  int*   mskA=(int*)  alloc((size_t)EE*4);
  int*   srcB=(int*)  alloc((size_t)EE*4);
  int*   dstB=(int*)  alloc((size_t)EE*4);
  int*   mskB=(int*)  alloc((size_t)EE*4);
  float* xf  =(float*)alloc((size_t)BB*256*4);
  float* z1  =(float*)alloc((size_t)BB*DD*4);
  float* h1b =(float*)alloc((size_t)BB*DD*4);
  float* z2  =(float*)alloc((size_t)BB*HIDD*4);
  float* h2b =(float*)alloc((size_t)BB*HIDD*4);

  const int npg[3]={400,320,256};
  const int kpg[3]={320,256,205};
  const int Nin[3]={BB*400, BB*320, BB*256};

  hipMemsetAsync(xf,0,(size_t)BB*256*4,stream);
  k_pos<<<2048,256,0,stream>>>(x_in,lap,Wpos,bpos,xA,Nin[0]);

  const int* src=esrc0; const int* dst=edst0; const int* msk=nullptr;

  for(int i=0;i<3;i++){
    int N=Nin[i];
    int gB=N/64;
    const float* Wq=gWq+(size_t)i*DD*DD;   const float* bq=gbq+(size_t)i*DD;
    const float* Wk=gWk+(size_t)i*DD*DD;   const float* bk=gbk+(size_t)i*DD;
    const float* Wv=gWv+(size_t)i*DD*DD;   const float* bv=gbv+(size_t)i*DD;
    const float* Ws=gWs+(size_t)i*DD*DD;   const float* bs=gbs+(size_t)i*DD;
    const float* Wlo=gWlo+(size_t)i*DD*DD; const float* blo=gblo+(size_t)i*DD;
    const float* l1g=gl1g+(size_t)i*DD;    const float* l1b=gl1b+(size_t)i*DD;
    const float* W1=gW1+(size_t)i*DD*HIDD; const float* b1=gb1+(size_t)i*HIDD;
    const float* W2=gW2+(size_t)i*HIDD*DD; const float* b2=gb2+(size_t)i*DD;
    const float* l2g=gl2g+(size_t)i*DD;    const float* l2b=gl2b+(size_t)i*DD;
    const float* wrel=pWrel+(size_t)i*DD;  const float* brel=pbrel+(size_t)i;
    const float* wrt=pWrt+(size_t)i*DD;

    // CSR build (layers 1,2: fused remap of previous layer's edges via kept/nid)
    if(i==0){
      k_csr<<<BB,512,0,stream>>>(src,dst,nullptr,nullptr,nullptr,npg[i],
                                 rowstart,rowcnt,esrcW,nullptr,nullptr,nullptr);
    } else {
      int* ns=(i==1)?srcA:srcB; int* ndd=(i==1)?dstA:dstB; int* nm=(i==1)?mskA:mskB;
      k_csr<<<BB,512,0,stream>>>(src,dst,msk,kept,nid,npg[i],
                                 rowstart,rowcnt,esrcW,ns,ndd,nm);
      src=ns; dst=ndd; msk=nm;
    }

    // TransformerConv projections (Q,K,V,skip) — 2-D grid, 4x wave parallelism
    k_gemm4_sw<<<dim3(gB,4),512,0,stream>>>(xA,Wq,Wk,Wv,Ws,bq,bk,bv,bs,qb,kb,vb,xO);
    if(i==0)      k_attn4<400><<<BB*HH,512,0,stream>>>(qb,kb,vb,rowstart,rowcnt,esrcW,xO);
    else if(i==1) k_attn4<320><<<BB*HH,512,0,stream>>>(qb,kb,vb,rowstart,rowcnt,esrcW,xO);
    else          k_attn4<256><<<BB*HH,512,0,stream>>>(qb,kb,vb,rowstart,rowcnt,esrcW,xO);
    // fused FFN (1024 threads, 16 waves, wave-uniform slices)
    k_ffn_fused<<<gB,1024,0,stream>>>(xO,xA,Wlo,blo,l1g,l1b,W1,b1,W2,b2,l2g,l2b,xO);

    // SAGPool: scorer + top-k fused (per-graph block)
    k_sagtopk<<<BB,512,0,stream>>>(xO,wrel,wrt,brel,rowstart,rowcnt,esrcW,
                                   npg[i],kpg[i],tvb,gib,kept,nid);
    int rows=BB*kpg[i];
    k_gather<<<(rows*DD+255)/256,256,0,stream>>>(xO,gib,tvb,xA,rows);
    k_readout<<<BB,512,0,stream>>>(xA,kpg[i],xf);
  }

  // head MLP with BatchNorm (parallel kernels)
  k_h1<<<(BB*DD+127)/128,128,0,stream>>>(xf,hW1,hb1,z1);
  k_bnrelu<<<1,128,0,stream>>>(z1,bn1g,bn1b,h1b,DD);
  k_h2<<<(BB*HIDD+127)/128,128,0,stream>>>(h1b,hW2,hb2,z2);
  k_bnrelu<<<1,64,0,stream>>>(z2,bn2g,bn2b,h2b,HIDD);
  k_h3<<<1,64,0,stream>>>(h2b,hW3,hb3,out);
}

// Round 20
// 536.354 us; speedup vs baseline: 1.0467x; 1.0467x over previous
//
#include <hip/hip_runtime.h>
#include <math.h>

#define BB   64
#define NPG0 400
#define DD   128
#define HH   4
#define CC   32
#define HIDD 64
#define POSD 16
#define EE   409600
#define EG   6400

// ---------------- pos enc: out = x + lap @ Wpos + bpos ----------------
__global__ void k_pos(const float* __restrict__ x, const float* __restrict__ lap,
                      const float* __restrict__ Wp, const float* __restrict__ bp,
                      float* __restrict__ out, int N){
  __shared__ float W[POSD*DD];
  __shared__ float bsh[DD];
  for(int i=threadIdx.x;i<POSD*DD;i+=blockDim.x) W[i]=Wp[i];
  for(int i=threadIdx.x;i<DD;i+=blockDim.x) bsh[i]=bp[i];
  __syncthreads();
  int total=N*DD;
  for(int idx=blockIdx.x*blockDim.x+threadIdx.x; idx<total; idx+=gridDim.x*blockDim.x){
    int n=idx>>7, d=idx&127;
    const float* lr=lap+(size_t)n*POSD;
    float acc=bsh[d]+x[idx];
    #pragma unroll
    for(int p=0;p<POSD;p++) acc=fmaf(lr[p],W[p*DD+d],acc);
    out[idx]=acc;
  }
}

// ======== QKVS GEMM, 2-D grid: blockIdx.y selects matrix (4x wave parallelism) ====
// BM=64, 512 thr = 8 waves; wave w owns cols [w*16,(w+1)*16); lane = row.
__global__ __launch_bounds__(512) void k_gemm4_sw(
    const float* __restrict__ X,
    const float* __restrict__ W0,const float* __restrict__ W1,
    const float* __restrict__ W2,const float* __restrict__ W3,
    const float* __restrict__ b0,const float* __restrict__ b1,
    const float* __restrict__ b2,const float* __restrict__ b3,
    float* __restrict__ Y0,float* __restrict__ Y1,
    float* __restrict__ Y2,float* __restrict__ Y3){
  constexpr int XPAD=DD+4;
  __shared__ float Xl[64*XPAD];
  int my=blockIdx.y;
  const float* Wg  =(my==0)?W0:(my==1)?W1:(my==2)?W2:W3;
  const float* bias=(my==0)?b0:(my==1)?b1:(my==2)?b2:b3;
  float*       Y   =(my==0)?Y0:(my==1)?Y1:(my==2)?Y2:Y3;
  int tid=threadIdx.x;
  { const float4* xs=(const float4*)(X+(size_t)blockIdx.x*64*DD);
    for(int i=tid;i<64*32;i+=512){
      int r=i>>5, kq=i&31;
      *(float4*)&Xl[r*XPAD+kq*4]=xs[i];
    } }
  __syncthreads();
  int lane=tid&63;
  int wv=__builtin_amdgcn_readfirstlane(tid>>6);
  int cbase=wv*16;
  int row=blockIdx.x*64+lane;
  const float* xr=&Xl[lane*XPAD];
  float acc[16];
  #pragma unroll
  for(int c=0;c<16;c++) acc[c]=0.f;
  #pragma unroll 2
  for(int kt=0;kt<32;kt++){
    float4 xv=*(const float4*)&xr[4*kt];
    float xk[4]={xv.x,xv.y,xv.z,xv.w};
    #pragma unroll
    for(int kk=0;kk<4;kk++){
      const float4* wrow=(const float4*)(Wg+(size_t)(4*kt+kk)*DD+cbase);
      #pragma unroll
      for(int cg=0;cg<4;cg++){
        float4 w4=wrow[cg];
        acc[cg*4+0]=fmaf(xk[kk],w4.x,acc[cg*4+0]);
        acc[cg*4+1]=fmaf(xk[kk],w4.y,acc[cg*4+1]);
        acc[cg*4+2]=fmaf(xk[kk],w4.z,acc[cg*4+2]);
        acc[cg*4+3]=fmaf(xk[kk],w4.w,acc[cg*4+3]);
      }
    }
  }
  const float4* bb4=(const float4*)(bias+cbase);
  #pragma unroll
  for(int cg=0;cg<4;cg++){
    float4 b4=bb4[cg];
    float4 v;
    v.x=acc[cg*4+0]+b4.x; v.y=acc[cg*4+1]+b4.y;
    v.z=acc[cg*4+2]+b4.z; v.w=acc[cg*4+3]+b4.w;
    *(float4*)&Y[(size_t)row*DD+cbase+cg*4]=v;
  }
}

// ---- fused FFN chain: t2=LN(X@Wlo+b+resid); h=relu(t2@W1+b1); out=LN(h@W2+b2+t2) ----
__global__ __launch_bounds__(512) void k_ffn_fused(
    const float* __restrict__ Xg, const float* __restrict__ resid,
    const float* __restrict__ Wlo, const float* __restrict__ blo,
    const float* __restrict__ l1g, const float* __restrict__ l1b,
    const float* __restrict__ W1, const float* __restrict__ b1,
    const float* __restrict__ W2, const float* __restrict__ b2,
    const float* __restrict__ l2g, const float* __restrict__ l2b,
    float* __restrict__ Y){
  constexpr int XPAD=DD+4;
  constexpr int HPAD=HIDD+4;
  __shared__ float Xa[64*XPAD];
  __shared__ float hb[64*HPAD];
  __shared__ float redA[8*64];
  __shared__ float redB[8*64];
  int tid=threadIdx.x;
  { const float4* xs=(const float4*)(Xg+(size_t)blockIdx.x*64*DD);
    for(int i=tid;i<64*32;i+=512){
      int r=i>>5, kq=i&31;
      *(float4*)&Xa[r*XPAD+kq*4]=xs[i];
    } }
  __syncthreads();
  int lane=tid&63;
  int wv=__builtin_amdgcn_readfirstlane(tid>>6);
  int row=blockIdx.x*64+lane;
  const float* xr=&Xa[lane*XPAD];

  // ---- stage A: acc = X @ Wlo + blo + resid, LN -> t2 (in place) ----
  int cbase=wv*16;
  float acc[16];
  #pragma unroll
  for(int c=0;c<16;c++) acc[c]=0.f;
  #pragma unroll 2
  for(int kt=0;kt<32;kt++){
    float4 xv=*(const float4*)&xr[4*kt];
    float xk[4]={xv.x,xv.y,xv.z,xv.w};
    #pragma unroll
    for(int kk=0;kk<4;kk++){
      const float4* wrow=(const float4*)(Wlo+(size_t)(4*kt+kk)*DD+cbase);
      #pragma unroll
      for(int cg=0;cg<4;cg++){
        float4 w4=wrow[cg];
        acc[cg*4+0]=fmaf(xk[kk],w4.x,acc[cg*4+0]);
        acc[cg*4+1]=fmaf(xk[kk],w4.y,acc[cg*4+1]);
        acc[cg*4+2]=fmaf(xk[kk],w4.z,acc[cg*4+2]);
        acc[cg*4+3]=fmaf(xk[kk],w4.w,acc[cg*4+3]);
      }
    }
  }
  { const float4* bb4=(const float4*)(blo+cbase);
    #pragma unroll
    for(int cg=0;cg<4;cg++){
      float4 b4=bb4[cg];
      float4 rv=*(const float4*)&resid[(size_t)row*DD+cbase+cg*4];
      acc[cg*4+0]+=b4.x+rv.x; acc[cg*4+1]+=b4.y+rv.y;
      acc[cg*4+2]+=b4.z+rv.z; acc[cg*4+3]+=b4.w+rv.w;
    } }
  { float ps=0.f,pq=0.f;
    #pragma unroll
    for(int c=0;c<16;c++){ ps+=acc[c]; pq+=acc[c]*acc[c]; }
    redA[wv*64+lane]=ps; redB[wv*64+lane]=pq;
    __syncthreads();
    float s=0.f,q=0.f;
    #pragma unroll
    for(int w=0;w<8;w++){ s+=redA[w*64+lane]; q+=redB[w*64+lane]; }
    float mu=s*(1.f/DD);
    float inv=1.0f/sqrtf(q*(1.f/DD)-mu*mu+1e-5f);
    const float4* g4p=(const float4*)(l1g+cbase);
    const float4* e4p=(const float4*)(l1b+cbase);
    #pragma unroll
    for(int cg=0;cg<4;cg++){
      float4 g4=g4p[cg], e4=e4p[cg];
      float4 v;
      v.x=(acc[cg*4+0]-mu)*inv*g4.x+e4.x;
      v.y=(acc[cg*4+1]-mu)*inv*g4.y+e4.y;
      v.z=(acc[cg*4+2]-mu)*inv*g4.z+e4.z;
      v.w=(acc[cg*4+3]-mu)*inv*g4.w+e4.w;
      *(float4*)&Xa[lane*XPAD+cbase+cg*4]=v;
    } }
  __syncthreads();

  // ---- stage B: h = relu(t2 @ W1 + b1) ----
  { int cb2=wv*8;
    float acc2[8];
    #pragma unroll
    for(int c=0;c<8;c++) acc2[c]=0.f;
    #pragma unroll 2
    for(int kt=0;kt<32;kt++){
      float4 xv=*(const float4*)&xr[4*kt];
      float xk[4]={xv.x,xv.y,xv.z,xv.w};
      #pragma unroll
      for(int kk=0;kk<4;kk++){
        const float4* wrow=(const float4*)(W1+(size_t)(4*kt+kk)*HIDD+cb2);
        #pragma unroll
        for(int cg=0;cg<2;cg++){
          float4 w4=wrow[cg];
          acc2[cg*4+0]=fmaf(xk[kk],w4.x,acc2[cg*4+0]);
          acc2[cg*4+1]=fmaf(xk[kk],w4.y,acc2[cg*4+1]);
          acc2[cg*4+2]=fmaf(xk[kk],w4.z,acc2[cg*4+2]);
          acc2[cg*4+3]=fmaf(xk[kk],w4.w,acc2[cg*4+3]);
        }
      }
    }
    const float4* bb4=(const float4*)(b1+cb2);
    #pragma unroll
    for(int cg=0;cg<2;cg++){
      float4 b4=bb4[cg];
      float4 v;
      v.x=fmaxf(acc2[cg*4+0]+b4.x,0.f); v.y=fmaxf(acc2[cg*4+1]+b4.y,0.f);
      v.z=fmaxf(acc2[cg*4+2]+b4.z,0.f); v.w=fmaxf(acc2[cg*4+3]+b4.w,0.f);
      *(float4*)&hb[lane*HPAD+cb2+cg*4]=v;
    } }
  __syncthreads();

  // ---- stage C: out = LN(h @ W2 + b2 + t2) ----
  { float acc3[16];
    #pragma unroll
    for(int c=0;c<16;c++) acc3[c]=0.f;
    const float* hr=&hb[lane*HPAD];
    #pragma unroll 2
    for(int kt=0;kt<16;kt++){
      float4 xv=*(const float4*)&hr[4*kt];
      float xk[4]={xv.x,xv.y,xv.z,xv.w};
      #pragma unroll
      for(int kk=0;kk<4;kk++){
        const float4* wrow=(const float4*)(W2+(size_t)(4*kt+kk)*DD+cbase);
        #pragma unroll
        for(int cg=0;cg<4;cg++){
          float4 w4=wrow[cg];
          acc3[cg*4+0]=fmaf(xk[kk],w4.x,acc3[cg*4+0]);
          acc3[cg*4+1]=fmaf(xk[kk],w4.y,acc3[cg*4+1]);
          acc3[cg*4+2]=fmaf(xk[kk],w4.z,acc3[cg*4+2]);
          acc3[cg*4+3]=fmaf(xk[kk],w4.w,acc3[cg*4+3]);
        }
      }
    }
    const float4* bb4=(const float4*)(b2+cbase);
    #pragma unroll
    for(int cg=0;cg<4;cg++){
      float4 b4=bb4[cg];
      float4 rv=*(const float4*)&Xa[lane*XPAD+cbase+cg*4];
      acc3[cg*4+0]+=b4.x+rv.x; acc3[cg*4+1]+=b4.y+rv.y;
      acc3[cg*4+2]+=b4.z+rv.z; acc3[cg*4+3]+=b4.w+rv.w;
    }
    float ps=0.f,pq=0.f;
    #pragma unroll
    for(int c=0;c<16;c++){ ps+=acc3[c]; pq+=acc3[c]*acc3[c]; }
    __syncthreads();
    redA[wv*64+lane]=ps; redB[wv*64+lane]=pq;
    __syncthreads();
    float s=0.f,q=0.f;
    #pragma unroll
    for(int w=0;w<8;w++){ s+=redA[w*64+lane]; q+=redB[w*64+lane]; }
    float mu=s*(1.f/DD);
    float inv=1.0f/sqrtf(q*(1.f/DD)-mu*mu+1e-5f);
    const float4* g4p=(const float4*)(l2g+cbase);
    const float4* e4p=(const float4*)(l2b+cbase);
    #pragma unroll
    for(int cg=0;cg<4;cg++){
      float4 g4=g4p[cg], e4=e4p[cg];
      float4 v;
      v.x=(acc3[cg*4+0]-mu)*inv*g4.x+e4.x;
      v.y=(acc3[cg*4+1]-mu)*inv*g4.y+e4.y;
      v.z=(acc3[cg*4+2]-mu)*inv*g4.z+e4.z;
      v.w=(acc3[cg*4+3]-mu)*inv*g4.w+e4.w;
      *(float4*)&Y[(size_t)row*DD+cbase+cg*4]=v;
    } }
}

// ---------------- per-graph destination-CSR with fused remap ----------------
__global__ __launch_bounds__(512) void k_csr(const int* __restrict__ src,const int* __restrict__ dst,
   const int* __restrict__ msk,const int* __restrict__ kept,const int* __restrict__ nid,int n,
   int* __restrict__ rowstart,int* __restrict__ rowcnt,int* __restrict__ esrc,
   int* __restrict__ nsrc,int* __restrict__ ndst,int* __restrict__ nmsk){
  __shared__ int cnt[512];
  __shared__ int woff[512];
  int b=blockIdx.x, t=threadIdx.x;
  cnt[t]=0;
  __syncthreads();
  int ebase=b*EG, nbase=b*n;
  for(int j=t;j<EG;j+=512){
    int e=ebase+j;
    int s,d,m;
    if(kept){
      int s0=src[e], d0=dst[e];
      m=(msk?msk[e]:1) && kept[s0] && kept[d0];
      s=m?nid[s0]:0; d=m?nid[d0]:0;
      nsrc[e]=s; ndst[e]=d; nmsk[e]=m;
    } else { s=src[e]; d=dst[e]; m=1; }
    if(m) atomicAdd(&cnt[d-nbase],1);
  }
  __syncthreads();
  int v=cnt[t];
  woff[t]=v;
  __syncthreads();
  for(int off=1;off<512;off<<=1){
    int a=(t>=off)?woff[t-off]:0;
    __syncthreads();
    woff[t]+=a;
    __syncthreads();
  }
  int excl=woff[t]-v;
  if(t<n){ rowstart[nbase+t]=ebase+excl; rowcnt[nbase+t]=v; }
  __syncthreads();
  woff[t]=excl;
  __syncthreads();
  for(int j=t;j<EG;j+=512){
    int e=ebase+j;
    int s,d,m;
    if(kept){ m=nmsk[e]; s=nsrc[e]; d=ndst[e]; }
    else { m=1; s=src[e]; d=dst[e]; }
    if(!m) continue;
    int off=atomicAdd(&woff[d-nbase],1);
    esrc[ebase+off]=s;
  }
}

// ---------------- fused attention: one LANE per (node,head), padded K/V in LDS ----
template<int NG>
__global__ __launch_bounds__(512) void k_attn4(const float* __restrict__ q,const float* __restrict__ kk,
     const float* __restrict__ v,const int* __restrict__ rowstart,const int* __restrict__ rowcnt,
     const int* __restrict__ esrc,float* __restrict__ attn){
  __shared__ float4 kl[NG*9];
  __shared__ float4 vl[NG*9];
  int b=blockIdx.x>>2, h=blockIdx.x&3;
  int nb=b*NG;
  const float4* kg=(const float4*)kk;
  const float4* vg=(const float4*)v;
  for(int i=threadIdx.x;i<NG*8;i+=512){
    int node=i>>3, qq=i&7;
    size_t gidx=(size_t)(nb+node)*32 + h*8 + qq;
    kl[node*9+qq]=kg[gidx];
    vl[node*9+qq]=vg[gidx];
  }
  __syncthreads();
  int node=threadIdx.x;
  if(node>=NG) return;
  int gn=nb+node;
  float4 q0,q1,q2,q3,q4,q5,q6,q7;
  { const float4* qp=(const float4*)(q+(size_t)gn*DD+h*CC);
    q0=qp[0];q1=qp[1];q2=qp[2];q3=qp[3];q4=qp[4];q5=qp[5];q6=qp[6];q7=qp[7]; }
  int st=rowstart[gn], cn=rowcnt[gn];
  float m=-1e30f, s=0.f;
  float4 o0={0,0,0,0},o1={0,0,0,0},o2={0,0,0,0},o3={0,0,0,0};
  float4 o4={0,0,0,0},o5={0,0,0,0},o6={0,0,0,0},o7={0,0,0,0};
  for(int j=0;j<cn;j++){
    int sl=esrc[st+j]-nb;
    const float4* kr=&kl[sl*9];
    float4 k0=kr[0],k1=kr[1],k2=kr[2],k3=kr[3],k4=kr[4],k5=kr[5],k6=kr[6],k7=kr[7];
    float a0=q0.x*k0.x+q0.y*k0.y+q0.z*k0.z+q0.w*k0.w;
    float a1=q1.x*k1.x+q1.y*k1.y+q1.z*k1.z+q1.w*k1.w;
    float a2=q2.x*k2.x+q2.y*k2.y+q2.z*k2.z+q2.w*k2.w;
    float a3=q3.x*k3.x+q3.y*k3.y+q3.z*k3.z+q3.w*k3.w;
    a0+=q4.x*k4.x+q4.y*k4.y+q4.z*k4.z+q4.w*k4.w;
    a1+=q5.x*k5.x+q5.y*k5.y+q5.z*k5.z+q5.w*k5.w;
    a2+=q6.x*k6.x+q6.y*k6.y+q6.z*k6.z+q6.w*k6.w;
    a3+=q7.x*k7.x+q7.y*k7.y+q7.z*k7.z+q7.w*k7.w;
    float lg=((a0+a1)+(a2+a3))*0.17677669529663687f;
    const float4* vr=&vl[sl*9];
    float4 v0=vr[0],v1=vr[1],v2=vr[2],v3=vr[3],v4=vr[4],v5=vr[5],v6=vr[6],v7=vr[7];
    if(lg<=m){
      float w=__expf(lg-m);
      s+=w;
      o0.x=fmaf(w,v0.x,o0.x);o0.y=fmaf(w,v0.y,o0.y);o0.z=fmaf(w,v0.z,o0.z);o0.w=fmaf(w,v0.w,o0.w);
      o1.x=fmaf(w,v1.x,o1.x);o1.y=fmaf(w,v1.y,o1.y);o1.z=fmaf(w,v1.z,o1.z);o1.w=fmaf(w,v1.w,o1.w);
      o2.x=fmaf(w,v2.x,o2.x);o2.y=fmaf(w,v2.y,o2.y);o2.z=fmaf(w,v2.z,o2.z);o2.w=fmaf(w,v2.w,o2.w);
      o3.x=fmaf(w,v3.x,o3.x);o3.y=fmaf(w,v3.y,o3.y);o3.z=fmaf(w,v3.z,o3.z);o3.w=fmaf(w,v3.w,o3.w);
      o4.x=fmaf(w,v4.x,o4.x);o4.y=fmaf(w,v4.y,o4.y);o4.z=fmaf(w,v4.z,o4.z);o4.w=fmaf(w,v4.w,o4.w);
      o5.x=fmaf(w,v5.x,o5.x);o5.y=fmaf(w,v5.y,o5.y);o5.z=fmaf(w,v5.z,o5.z);o5.w=fmaf(w,v5.w,o5.w);
      o6.x=fmaf(w,v6.x,o6.x);o6.y=fmaf(w,v6.y,o6.y);o6.z=fmaf(w,v6.z,o6.z);o6.w=fmaf(w,v6.w,o6.w);
      o7.x=fmaf(w,v7.x,o7.x);o7.y=fmaf(w,v7.y,o7.y);o7.z=fmaf(w,v7.z,o7.z);o7.w=fmaf(w,v7.w,o7.w);
    } else {
      float r=__expf(m-lg);
      s=fmaf(s,r,1.f);
      o0.x=fmaf(o0.x,r,v0.x);o0.y=fmaf(o0.y,r,v0.y);o0.z=fmaf(o0.z,r,v0.z);o0.w=fmaf(o0.w,r,v0.w);
      o1.x=fmaf(o1.x,r,v1.x);o1.y=fmaf(o1.y,r,v1.y);o1.z=fmaf(o1.z,r,v1.z);o1.w=fmaf(o1.w,r,v1.w);
      o2.x=fmaf(o2.x,r,v2.x);o2.y=fmaf(o2.y,r,v2.y);o2.z=fmaf(o2.z,r,v2.z);o2.w=fmaf(o2.w,r,v2.w);
      o3.x=fmaf(o3.x,r,v3.x);o3.y=fmaf(o3.y,r,v3.y);o3.z=fmaf(o3.z,r,v3.z);o3.w=fmaf(o3.w,r,v3.w);
      o4.x=fmaf(o4.x,r,v4.x);o4.y=fmaf(o4.y,r,v4.y);o4.z=fmaf(o4.z,r,v4.z);o4.w=fmaf(o4.w,r,v4.w);
      o5.x=fmaf(o5.x,r,v5.x);o5.y=fmaf(o5.y,r,v5.y);o5.z=fmaf(o5.z,r,v5.z);o5.w=fmaf(o5.w,r,v5.w);
      o6.x=fmaf(o6.x,r,v6.x);o6.y=fmaf(o6.y,r,v6.y);o6.z=fmaf(o6.z,r,v6.z);o6.w=fmaf(o6.w,r,v6.w);
      o7.x=fmaf(o7.x,r,v7.x);o7.y=fmaf(o7.y,r,v7.y);o7.z=fmaf(o7.z,r,v7.z);o7.w=fmaf(o7.w,r,v7.w);
      m=lg;
    }
  }
  float inv=(s>0.f)?(1.f/s):0.f;
  float* op=attn+(size_t)gn*DD+h*CC;
  float4* op4=(float4*)op;
  float4 r0=op4[0],r1=op4[1],r2=op4[2],r3=op4[3],r4=op4[4],r5=op4[5],r6=op4[6],r7=op4[7];
  r0.x+=o0.x*inv;r0.y+=o0.y*inv;r0.z+=o0.z*inv;r0.w+=o0.w*inv;
  r1.x+=o1.x*inv;r1.y+=o1.y*inv;r1.z+=o1.z*inv;r1.w+=o1.w*inv;
  r2.x+=o2.x*inv;r2.y+=o2.y*inv;r2.z+=o2.z*inv;r2.w+=o2.w*inv;
  r3.x+=o3.x*inv;r3.y+=o3.y*inv;r3.z+=o3.z*inv;r3.w+=o3.w*inv;
  r4.x+=o4.x*inv;r4.y+=o4.y*inv;r4.z+=o4.z*inv;r4.w+=o4.w*inv;
  r5.x+=o5.x*inv;r5.y+=o5.y*inv;r5.z+=o5.z*inv;r5.w+=o5.w*inv;
  r6.x+=o6.x*inv;r6.y+=o6.y*inv;r6.z+=o6.z*inv;r6.w+=o6.w*inv;
  r7.x+=o7.x*inv;r7.y+=o7.y*inv;r7.z+=o7.z*inv;r7.w+=o7.w*inv;
  op4[0]=r0;op4[1]=r1;op4[2]=r2;op4[3]=r3;op4[4]=r4;op4[5]=r5;op4[6]=r6;op4[7]=r7;
}

// ---------------- fused SAGPool scorer + top-k (block per graph) ----------------
__global__ __launch_bounds__(512) void k_sagtopk(const float* __restrict__ x,
   const float* __restrict__ wrel,const float* __restrict__ wroot,const float* __restrict__ brel,
   const int* __restrict__ rowstart,const int* __restrict__ rowcnt,const int* __restrict__ esrc,
   int n,int k,float* __restrict__ tv,int* __restrict__ gi,
   int* __restrict__ kept,int* __restrict__ nid){
  __shared__ float pnl[NPG0];
  __shared__ float sv[512];
  __shared__ int   si[512];
  int b=blockIdx.x, t=threadIdx.x, nbase=b*n;
  float rdot=0.f;
  if(t<n){
    const float4* xr=(const float4*)(x+(size_t)(nbase+t)*DD);
    float p=0.f;
    #pragma unroll
    for(int qq=0;qq<32;qq++){
      float4 xv=xr[qq];
      float4 wr=((const float4*)wrel)[qq];
      float4 wo=((const float4*)wroot)[qq];
      p   =fmaf(xv.x,wr.x,fmaf(xv.y,wr.y,fmaf(xv.z,wr.z,fmaf(xv.w,wr.w,p))));
      rdot=fmaf(xv.x,wo.x,fmaf(xv.y,wo.y,fmaf(xv.z,wo.z,fmaf(xv.w,wo.w,rdot))));
    }
    pnl[t]=p;
  }
  __syncthreads();
  float sc=-INFINITY;
  if(t<n){
    int st=rowstart[nbase+t], cn=rowcnt[nbase+t];
    float s=0.f;
    for(int j=0;j<cn;j++) s+=pnl[esrc[st+j]-nbase];
    sc=tanhf(s+brel[0]+rdot);
  }
  sv[t]=(t<n)?sc:-INFINITY;
  si[t]=t;
  for(int ksz=2;ksz<=512;ksz<<=1){
    for(int j=ksz>>1;j>0;j>>=1){
      __syncthreads();
      int ixj=t^j;
      if(ixj>t){
        float s1=sv[t], s2=sv[ixj];
        int i1=si[t], i2=si[ixj];
        bool firstRanks=(s1>s2)||(s1==s2&&i1<i2);
        bool up=((t&ksz)==0);
        if(up? !firstRanks : firstRanks){ sv[t]=s2;sv[ixj]=s1;si[t]=i2;si[ixj]=i1; }
      }
    }
  }
  __syncthreads();
  if(t<k){
    int oldg=nbase+si[t];
    tv[b*k+t]=sv[t];
    gi[b*k+t]=oldg;
    kept[oldg]=1;
    nid[oldg]=b*k+t;
  } else if(t<n){
    kept[nbase+si[t]]=0;
  }
}

// ---------------- gather (parallel) ----------------
__global__ void k_gather(const float* __restrict__ xin, const int* __restrict__ gi,
                         const float* __restrict__ tv, float* __restrict__ xout, int rows){
  int idx=blockIdx.x*blockDim.x+threadIdx.x;
  if(idx>=rows*DD) return;
  int r=idx>>7;
  int d=idx&127;
  xout[idx]=xin[(size_t)gi[r]*DD+d]*tv[r];
}

// ---------------- readout (4 j-strips x 128 channels per block) ----------------
__global__ __launch_bounds__(512) void k_readout(const float* __restrict__ xk, int k,
                                                 float* __restrict__ xf){
  __shared__ float pm[512];
  __shared__ float ps[512];
  int b=blockIdx.x, t=threadIdx.x;
  int d=t&127, strip=t>>7;
  const float* base=xk+((size_t)b*k)*DD+d;
  float mx=-INFINITY, sm=0.f;
  for(int j=strip;j<k;j+=4){
    float v=base[(size_t)j*DD];
    mx=fmaxf(mx,v); sm+=v;
  }
  pm[t]=mx; ps[t]=sm;
  __syncthreads();
  if(t<128){
    float m0=fmaxf(fmaxf(pm[t],pm[t+128]),fmaxf(pm[t+256],pm[t+384]));
    float s0=ps[t]+ps[t+128]+ps[t+256]+ps[t+384];
    xf[b*256+t]+=m0;
    xf[b*256+128+t]+=s0/(float)k;
  }
}

// ---------------- head (parallel, unfused) ----------------
__global__ void k_h1(const float* __restrict__ xf,const float* __restrict__ W,const float* __restrict__ b,float* __restrict__ z){
  int i=blockIdx.x*blockDim.x+threadIdx.x; if(i>=BB*DD) return;
  int r=i>>7, j=i&127;
  float acc=b[j];
  const float* xr=xf+r*256;
  #pragma unroll 8
  for(int t=0;t<256;t++) acc=fmaf(xr[t], W[t*DD+j], acc);
  z[i]=acc;
}
__global__ void k_bnrelu(const float* __restrict__ z,const float* __restrict__ g,const float* __restrict__ be,
                         float* __restrict__ h,int cols){
  int j=blockIdx.x*blockDim.x+threadIdx.x; if(j>=cols) return;
  float mu=0.f;
  for(int r=0;r<BB;r++) mu+=z[r*cols+j];
  mu*=(1.f/BB);
  float var=0.f;
  for(int r=0;r<BB;r++){ float d=z[r*cols+j]-mu; var+=d*d; }
  var*=(1.f/BB);
  float inv=1.0f/sqrtf(var+1e-5f);
  float gg=g[j], bb=be[j];
  for(int r=0;r<BB;r++){ float y=(z[r*cols+j]-mu)*inv*gg+bb; h[r*cols+j]=fmaxf(y,0.f); }
}
__global__ void k_h2(const float* __restrict__ h1,const float* __restrict__ W,const float* __restrict__ b,float* __restrict__ z){
  int i=blockIdx.x*blockDim.x+threadIdx.x; if(i>=BB*HIDD) return;
  int r=i>>6, j=i&63;
  float acc=b[j];
  #pragma unroll 8
  for(int t=0;t<DD;t++) acc=fmaf(h1[r*DD+t], W[t*HIDD+j], acc);
  z[i]=acc;
}
__global__ void k_h3(const float* __restrict__ h2,const float* __restrict__ W,const float* __restrict__ b,float* __restrict__ out){
  int bi=threadIdx.x; if(bi>=BB) return;
  float acc=b[0];
  for(int t=0;t<HIDD;t++) acc=fmaf(h2[bi*HIDD+t], W[t], acc);
  out[bi]=acc;
}

extern "C" void kernel_launch(void* const* d_in, const int* in_sizes, int n_in,
                              void* d_out, int out_size, void* d_ws, size_t ws_size,
                              hipStream_t stream){
  (void)in_sizes; (void)n_in; (void)out_size; (void)ws_size;
  const float* x_in =(const float*)d_in[0];
  const float* lap  =(const float*)d_in[1];
  const int*   esrc0=(const int*)  d_in[2];
  const int*   edst0=(const int*)  d_in[3];
  const float* Wpos =(const float*)d_in[4];
  const float* bpos =(const float*)d_in[5];
  const float* gWq  =(const float*)d_in[6];
  const float* gbq  =(const float*)d_in[7];
  const float* gWk  =(const float*)d_in[8];
  const float* gbk  =(const float*)d_in[9];
  const float* gWv  =(const float*)d_in[10];
  const float* gbv  =(const float*)d_in[11];
  const float* gWs  =(const float*)d_in[12];
  const float* gbs  =(const float*)d_in[13];
  const float* gWlo =(const float*)d_in[14];
  const float* gblo =(const float*)d_in[15];
  const float* gl1g =(const float*)d_in[16];
  const float* gl1b =(const float*)d_in[17];
  const float* gW1  =(const float*)d_in[18];
  const float* gb1  =(const float*)d_in[19];
  const float* gW2  =(const float*)d_in[20];
  const float* gb2  =(const float*)d_in[21];
  const float* gl2g =(const float*)d_in[22];
  const float* gl2b =(const float*)d_in[23];
  const float* pWrel=(const float*)d_in[24];
  const float* pbrel=(const float*)d_in[25];
  const float* pWrt =(const float*)d_in[26];
  const float* hW1  =(const float*)d_in[27];
  const float* hb1  =(const float*)d_in[28];
  const float* hW2  =(const float*)d_in[29];
  const float* hb2  =(const float*)d_in[30];
  const float* hW3  =(const float*)d_in[31];
  const float* hb3  =(const float*)d_in[32];
  const float* bn1g =(const float*)d_in[33];
  const float* bn1b =(const float*)d_in[34];
  const float* bn2g =(const float*)d_in[35];
  const float* bn2b =(const float*)d_in[36];
  float* out=(float*)d_out;

  // ---- workspace arena ----
  char* base=(char*)d_ws; size_t off=0;
  auto alloc=[&](size_t bytes)->void*{ void* p=base+off; off+=(bytes+255)&~(size_t)255; return p; };
  const int NMAX=BB*NPG0; // 25600
  float* xA  =(float*)alloc((size_t)NMAX*DD*4);
  float* qb  =(float*)alloc((size_t)NMAX*DD*4);
  float* kb  =(float*)alloc((size_t)NMAX*DD*4);
  float* vb  =(float*)alloc((size_t)NMAX*DD*4);
  float* xO  =(float*)alloc((size_t)NMAX*DD*4);   // skip/attn/block-output
  int*   rowstart=(int*)alloc((size_t)NMAX*4);
  int*   rowcnt  =(int*)alloc((size_t)NMAX*4);
  int*   esrcW   =(int*)alloc((size_t)EE*4);
  float* tvb =(float*)alloc((size_t)BB*320*4);
  int*   gib =(int*)  alloc((size_t)BB*320*4);
  int*   kept=(int*)  alloc((size_t)NMAX*4);
  int*   nid =(int*)  alloc((size_t)NMAX*4);
  int*   srcA=(int*)  alloc((size_t)EE*4);
  int*   dstA=(int*)  alloc((size_t)EE*4);
  int*   mskA=(int*)  alloc((size_t)EE*4);
  int*   srcB=(int*)  alloc((size_t)EE*4);
  int*   dstB=(int*)  alloc((size_t)EE*4);
  int*   mskB=(int*)  alloc((size_t)EE*4);
  float* xf  =(float*)alloc((size_t)BB*256*4);
  float* z1  =(float*)alloc((size_t)BB*DD*4);
  float* h1b =(float*)alloc((size_t)BB*DD*4);
  float* z2  =(float*)alloc((size_t)BB*HIDD*4);
  float* h2b =(float*)alloc((size_t)BB*HIDD*4);

  const int npg[3]={400,320,256};
  const int kpg[3]={320,256,205};
  const int Nin[3]={BB*400, BB*320, BB*256};

  hipMemsetAsync(xf,0,(size_t)BB*256*4,stream);
  k_pos<<<2048,256,0,stream>>>(x_in,lap,Wpos,bpos,xA,Nin[0]);

  const int* src=esrc0; const int* dst=edst0; const int* msk=nullptr;

  for(int i=0;i<3;i++){
    int N=Nin[i];
    int gB=N/64;
    const float* Wq=gWq+(size_t)i*DD*DD;   const float* bq=gbq+(size_t)i*DD;
    const float* Wk=gWk+(size_t)i*DD*DD;   const float* bk=gbk+(size_t)i*DD;
    const float* Wv=gWv+(size_t)i*DD*DD;   const float* bv=gbv+(size_t)i*DD;
    const float* Ws=gWs+(size_t)i*DD*DD;   const float* bs=gbs+(size_t)i*DD;
    const float* Wlo=gWlo+(size_t)i*DD*DD; const float* blo=gblo+(size_t)i*DD;
    const float* l1g=gl1g+(size_t)i*DD;    const float* l1b=gl1b+(size_t)i*DD;
    const float* W1=gW1+(size_t)i*DD*HIDD; const float* b1=gb1+(size_t)i*HIDD;
    const float* W2=gW2+(size_t)i*HIDD*DD; const float* b2=gb2+(size_t)i*DD;
    const float* l2g=gl2g+(size_t)i*DD;    const float* l2b=gl2b+(size_t)i*DD;
    const float* wrel=pWrel+(size_t)i*DD;  const float* brel=pbrel+(size_t)i;
    const float* wrt=pWrt+(size_t)i*DD;

    // CSR build (layers 1,2: fused remap of previous layer's edges via kept/nid)
    if(i==0){
      k_csr<<<BB,512,0,stream>>>(src,dst,nullptr,nullptr,nullptr,npg[i],
                                 rowstart,rowcnt,esrcW,nullptr,nullptr,nullptr);
    } else {
      int* ns=(i==1)?srcA:srcB; int* ndd=(i==1)?dstA:dstB; int* nm=(i==1)?mskA:mskB;
      k_csr<<<BB,512,0,stream>>>(src,dst,msk,kept,nid,npg[i],
                                 rowstart,rowcnt,esrcW,ns,ndd,nm);
      src=ns; dst=ndd; msk=nm;
    }

    // TransformerConv projections (Q,K,V,skip) — 2-D grid, 4x wave parallelism
    k_gemm4_sw<<<dim3(gB,4),512,0,stream>>>(xA,Wq,Wk,Wv,Ws,bq,bk,bv,bs,qb,kb,vb,xO);
    if(i==0)      k_attn4<400><<<BB*HH,512,0,stream>>>(qb,kb,vb,rowstart,rowcnt,esrcW,xO);
    else if(i==1) k_attn4<320><<<BB*HH,512,0,stream>>>(qb,kb,vb,rowstart,rowcnt,esrcW,xO);
    else          k_attn4<256><<<BB*HH,512,0,stream>>>(qb,kb,vb,rowstart,rowcnt,esrcW,xO);
    // fused: t2=LN(xO@Wlo+blo+xA); h=relu(t2@W1+b1); xO=LN(h@W2+b2+t2)
    k_ffn_fused<<<gB,512,0,stream>>>(xO,xA,Wlo,blo,l1g,l1b,W1,b1,W2,b2,l2g,l2b,xO);

    // SAGPool: scorer + top-k fused (per-graph block)
    k_sagtopk<<<BB,512,0,stream>>>(xO,wrel,wrt,brel,rowstart,rowcnt,esrcW,
                                   npg[i],kpg[i],tvb,gib,kept,nid);
    int rows=BB*kpg[i];
    k_gather<<<(rows*DD+255)/256,256,0,stream>>>(xO,gib,tvb,xA,rows);
    k_readout<<<BB,512,0,stream>>>(xA,kpg[i],xf);
  }

  // head MLP with BatchNorm (parallel kernels)
  k_h1<<<(BB*DD+127)/128,128,0,stream>>>(xf,hW1,hb1,z1);
  k_bnrelu<<<1,128,0,stream>>>(z1,bn1g,bn1b,h1b,DD);
  k_h2<<<(BB*HIDD+127)/128,128,0,stream>>>(h1b,hW2,hb2,z2);
  k_bnrelu<<<1,64,0,stream>>>(z2,bn2g,bn2b,h2b,HIDD);
  k_h3<<<1,64,0,stream>>>(h2b,hW3,hb3,out);
}